// Round 2
// baseline (214.258 us; speedup 1.0000x reference)
//
#include <hip/hip_runtime.h>
#include <hip/hip_bf16.h>
#include <math.h>

// Problem constants
#define NB   16      // batch
#define NIN  512
#define NN   2048
#define KN   28672   // K*N
#define KN4  7168    // KN/4

// ---------------------------------------------------------------------------
// k1: partial GEMM i_in = inputs @ W, accumulated in f64, deterministic.
// partials layout: part[ks][b][n], ks in [0,16), each ks covers 32 k's.
// grid (32 n-chunks, 4 k-blocks), block 256 = 64 n x 4 s.
__global__ __launch_bounds__(256) void k1_gemm(const float* __restrict__ inputs,
                                               const float* __restrict__ W,
                                               double* __restrict__ part) {
    __shared__ float inp[16 * 128];
    const int t = threadIdx.x;
    const int bx = blockIdx.x;   // n-chunk [0,32)
    const int by = blockIdx.y;   // k-block [0,4): covers 128 k's
    #pragma unroll
    for (int j = 0; j < 8; ++j) {
        int idx = t * 8 + j;
        int b = idx >> 7, kk = idx & 127;
        inp[idx] = inputs[b * NIN + by * 128 + kk];
    }
    __syncthreads();
    const int n_l = t & 63, s = t >> 6;
    const int n  = bx * 64 + n_l;
    const int ks = by * 4 + s;          // [0,16)
    const int k0 = ks * 32;
    double acc[16];
    #pragma unroll
    for (int b = 0; b < 16; ++b) acc[b] = 0.0;
    for (int kk = 0; kk < 32; ++kk) {
        double w = (double)W[(size_t)(k0 + kk) * NN + n];   // coalesced
        int lb = s * 32 + kk;                                // wave-uniform LDS addr
        #pragma unroll
        for (int b = 0; b < 16; ++b)
            acc[b] += w * (double)inp[b * 128 + lb];
    }
    #pragma unroll
    for (int b = 0; b < 16; ++b)
        part[(size_t)(ks * 16 + b) * NN + n] = acc[b];
}

// ---------------------------------------------------------------------------
// k2: deterministic reduce of 16 partials + LIF update. Writes new_z, new_v,
// and per-neuron 16-bit spike mask (atomicOr = order-independent).
__global__ __launch_bounds__(256) void k2_point(const double* __restrict__ part,
                                                const float* __restrict__ old_v,
                                                const float* __restrict__ old_spike,
                                                const int* __restrict__ tt_p,
                                                float* __restrict__ out,      // z @0, v @32768
                                                unsigned int* __restrict__ zmask) {
    int gid = blockIdx.x * 256 + threadIdx.x;   // [0, 32768)
    int b = gid >> 11, n = gid & (NN - 1);
    double s = 0.0;
    #pragma unroll
    for (int ks = 0; ks < 16; ++ks)             // fixed order -> deterministic
        s += part[(size_t)(ks * 16 + b) * NN + n];
    double tt   = (double)tt_p[0];
    double bias = 0.5 * sin(2.0 * 3.14159265358979323846 * 4.0 * (0.001 * tt));
    double d    = exp(-1.0 / 20.0);
    double i_in = s + bias;
    double nv   = d * (double)old_v[gid] + (1.0 - d) * i_in
                  - 0.03 * (double)old_spike[gid];
    bool z = nv > 0.03;                          // v_scaled > 0  <=>  nv > THR
    out[gid]           = z ? 1.0f : 0.0f;
    out[32768 + gid]   = (float)nv;
    if (z) atomicOr(&zmask[n], 1u << b);
}

// ---------------------------------------------------------------------------
// k3: streamed masked row-sum of B (= new_z @ B), n-chunked partials, no atomics.
// Masks staged in LDS (breaks the serial global-load chain); n-loop unrolled
// x8 with batched loads so 8 float4 loads are in flight per wave.
#define K3_UNROLL 8
__global__ __launch_bounds__(256) void k3_stream(const float4* __restrict__ B4,
                                                 const unsigned int* __restrict__ zmask,
                                                 float4* __restrict__ ZBp4,
                                                 int nper) {
    __shared__ unsigned int smask[512];
    const int t    = threadIdx.x;
    const int col4 = blockIdx.x * 256 + t;      // [0, 7168)
    const int n0   = blockIdx.y * nper;
    for (int j = t; j < nper; j += 256) smask[j] = zmask[n0 + j];
    __syncthreads();

    float4 acc[16];
    #pragma unroll
    for (int b = 0; b < 16; ++b) acc[b] = make_float4(0.f, 0.f, 0.f, 0.f);

    const float4* p = B4 + (size_t)n0 * KN4 + col4;
    for (int j = 0; j < nper; j += K3_UNROLL) {
        float4 v[K3_UNROLL];
        #pragma unroll
        for (int u = 0; u < K3_UNROLL; ++u)          // batched: 8 loads in flight
            v[u] = p[(size_t)(j + u) * KN4];
        #pragma unroll
        for (int u = 0; u < K3_UNROLL; ++u) {
            unsigned int m =
                (unsigned int)__builtin_amdgcn_readfirstlane((int)smask[j + u]);
            #pragma unroll
            for (int b = 0; b < 16; ++b) {
                if (m & (1u << b)) {                 // uniform -> scalar branch
                    acc[b].x += v[u].x; acc[b].y += v[u].y;
                    acc[b].z += v[u].z; acc[b].w += v[u].w;
                }
            }
        }
    }
    #pragma unroll
    for (int b = 0; b < 16; ++b)
        ZBp4[(size_t)(blockIdx.y * 16 + b) * KN4 + col4] = acc[b];
}

// ---------------------------------------------------------------------------
// k4: gather the 2048 indexed columns, reduce NC chunk-partials (fixed order).
__global__ __launch_bounds__(256) void k4_gather(const float* __restrict__ ZBp,
                                                 const int* __restrict__ ridx,
                                                 float* __restrict__ out_z2,
                                                 int NC) {
    int gid = blockIdx.x * 256 + threadIdx.x;   // [0, 32768)
    int b = gid >> 11, i = gid & (NN - 1);
    int r = ridx[i];
    float acc = 0.f;
    #pragma unroll 4
    for (int c = 0; c < NC; ++c)                // independent loads, pipelined
        acc += ZBp[(size_t)(c * 16 + b) * KN + r];
    out_z2[gid] = acc;
}

// ---------------------------------------------------------------------------
extern "C" void kernel_launch(void* const* d_in, const int* in_sizes, int n_in,
                              void* d_out, int out_size, void* d_ws, size_t ws_size,
                              hipStream_t stream) {
    const float* inputs    = (const float*)d_in[0];
    const float* old_v     = (const float*)d_in[1];
    const float* old_spike = (const float*)d_in[2];
    const float* W         = (const float*)d_in[3];
    const float* Bw        = (const float*)d_in[4];
    const int*   ridx      = (const int*)d_in[5];
    const int*   tt        = (const int*)d_in[6];
    float* out = (float*)d_out;

    // ws layout: [0,4MB) f64 i_in partials | [4MB,4MB+64KB) zmask | ZB partials
    char* ws = (char*)d_ws;
    double*       part  = (double*)ws;
    unsigned int* zmask = (unsigned int*)(ws + (4u << 20));
    float*        ZBp   = (float*)(ws + (4u << 20) + (64u << 10));

    size_t fixed = (4u << 20) + (64u << 10);
    size_t avail = ws_size > fixed ? ws_size - fixed : 0;
    int NC = 16;                                   // n-chunks for k3 (pow2)
    while (NC > 4 && (size_t)NC * 16 * KN * sizeof(float) > avail) NC >>= 1;
    int nper = NN / NC;                            // <= 512, multiple of 8

    hipMemsetAsync(zmask, 0, NN * sizeof(unsigned int), stream);
    k1_gemm <<<dim3(32, 4), 256, 0, stream>>>(inputs, W, part);
    k2_point<<<128, 256, 0, stream>>>(part, old_v, old_spike, tt, out, zmask);
    k3_stream<<<dim3(28, NC), 256, 0, stream>>>((const float4*)Bw, zmask,
                                                (float4*)ZBp, nper);
    k4_gather<<<128, 256, 0, stream>>>(ZBp, ridx, out + 65536, NC);
}

// Round 4
// 84.145 us; speedup vs baseline: 2.5463x; 2.5463x over previous
//
#include <hip/hip_runtime.h>
#include <hip/hip_bf16.h>
#include <math.h>

// Problem constants
#define NB   16      // batch
#define NIN  512
#define NN   2048
#define KN   28672   // K*N
#define KN2  14336   // KN/2

// ---------------------------------------------------------------------------
// k1: partial GEMM i_in = inputs @ W, f64 accumulation, deterministic order.
// part[ks][b][n], ks in [0,16) covering k = ks*32 .. ks*32+31.
// grid (32 n-chunks, 16 ks), block = 64 threads (one wave, 64 n's).
__global__ __launch_bounds__(64) void k1_gemm(const float* __restrict__ inputs,
                                              const float* __restrict__ W,
                                              double* __restrict__ part) {
    const int n  = blockIdx.x * 64 + threadIdx.x;
    const int ks = blockIdx.y;
    const int k0 = ks * 32;
    double acc[16];
    #pragma unroll
    for (int b = 0; b < 16; ++b) acc[b] = 0.0;
    #pragma unroll 4
    for (int kk = 0; kk < 32; ++kk) {
        double w = (double)W[(size_t)(k0 + kk) * NN + n];   // coalesced 256B/wave
        #pragma unroll
        for (int b = 0; b < 16; ++b)                        // uniform scalar loads
            acc[b] += w * (double)inputs[b * NIN + k0 + kk];
    }
    #pragma unroll
    for (int b = 0; b < 16; ++b)
        part[(size_t)(ks * 16 + b) * NN + n] = acc[b];
}

// ---------------------------------------------------------------------------
// k2: deterministic reduce of 16 partials + LIF update. Writes new_z, new_v,
// and per-neuron 16-bit spike mask (atomicOr = order-independent).
__global__ __launch_bounds__(256) void k2_point(const double* __restrict__ part,
                                                const float* __restrict__ old_v,
                                                const float* __restrict__ old_spike,
                                                const int* __restrict__ tt_p,
                                                float* __restrict__ out,      // z @0, v @32768
                                                unsigned int* __restrict__ zmask) {
    int gid = blockIdx.x * 256 + threadIdx.x;   // [0, 32768)
    int b = gid >> 11, n = gid & (NN - 1);
    double s = 0.0;
    #pragma unroll
    for (int ks = 0; ks < 16; ++ks)             // fixed order -> deterministic
        s += part[(size_t)(ks * 16 + b) * NN + n];
    double tt   = (double)tt_p[0];
    double bias = 0.5 * sin(2.0 * 3.14159265358979323846 * 4.0 * (0.001 * tt));
    double d    = 0.9512294245007140;           // exp(-1/20)
    double i_in = s + bias;
    double nv   = d * (double)old_v[gid] + (1.0 - d) * i_in
                  - 0.03 * (double)old_spike[gid];
    bool z = nv > 0.03;                          // v_scaled > 0  <=>  nv > THR
    out[gid]           = z ? 1.0f : 0.0f;
    out[32768 + gid]   = (float)nv;
    if (z) atomicOr(&zmask[n], 1u << b);
}

// ---------------------------------------------------------------------------
// k3: streamed masked row-sum of B (= new_z @ B).
// float2 per thread (keeps VGPR < 64: 32 acc + 16 in-flight), branchless
// selector-FMA with wave-uniform mask, UN=8 loads batched per iteration.
#define UN 8
__global__ __launch_bounds__(256) void k3_stream(const float2* __restrict__ B2,
                                                 const unsigned int* __restrict__ zmask,
                                                 float2* __restrict__ ZBp2,
                                                 int nper) {
    __shared__ unsigned int smask[1024];
    const int t    = threadIdx.x;
    const int col2 = blockIdx.x * 256 + t;       // [0, 14336)
    const int n0   = blockIdx.y * nper;
    for (int j = t; j < nper; j += 256) smask[j] = zmask[n0 + j];
    __syncthreads();

    float accx[16], accy[16];
    #pragma unroll
    for (int b = 0; b < 16; ++b) { accx[b] = 0.f; accy[b] = 0.f; }

    const float2* p = B2 + (size_t)n0 * KN2 + col2;
    for (int j = 0; j < nper; j += UN) {
        float2 v[UN];
        #pragma unroll
        for (int u = 0; u < UN; ++u)             // batched: 8 x 8B in flight
            v[u] = p[(size_t)(j + u) * KN2];
        #pragma unroll
        for (int u = 0; u < UN; ++u) {
            unsigned int m = (unsigned int)
                __builtin_amdgcn_readfirstlane((int)smask[j + u]);
            #pragma unroll
            for (int b = 0; b < 16; ++b) {
                float s = (m & (1u << b)) ? 1.0f : 0.0f;   // SGPR cselect
                accx[b] = fmaf(s, v[u].x, accx[b]);        // exact: +v or +0
                accy[b] = fmaf(s, v[u].y, accy[b]);
            }
        }
    }
    #pragma unroll
    for (int b = 0; b < 16; ++b) {
        float2 o; o.x = accx[b]; o.y = accy[b];
        ZBp2[(size_t)(blockIdx.y * 16 + b) * KN2 + col2] = o;
    }
}

// ---------------------------------------------------------------------------
// k4: gather the 2048 indexed columns, reduce NC chunk-partials (fixed order).
__global__ __launch_bounds__(256) void k4_gather(const float* __restrict__ ZBp,
                                                 const int* __restrict__ ridx,
                                                 float* __restrict__ out_z2,
                                                 int NC) {
    int gid = blockIdx.x * 256 + threadIdx.x;   // [0, 32768)
    int b = gid >> 11, i = gid & (NN - 1);
    int r = ridx[i];
    float acc = 0.f;
    #pragma unroll 4
    for (int c = 0; c < NC; ++c)                // independent loads, pipelined
        acc += ZBp[(size_t)(c * 16 + b) * KN + r];
    out_z2[gid] = acc;
}

// ---------------------------------------------------------------------------
extern "C" void kernel_launch(void* const* d_in, const int* in_sizes, int n_in,
                              void* d_out, int out_size, void* d_ws, size_t ws_size,
                              hipStream_t stream) {
    const float* inputs    = (const float*)d_in[0];
    const float* old_v     = (const float*)d_in[1];
    const float* old_spike = (const float*)d_in[2];
    const float* W         = (const float*)d_in[3];
    const float* Bw        = (const float*)d_in[4];
    const int*   ridx      = (const int*)d_in[5];
    const int*   tt        = (const int*)d_in[6];
    float* out = (float*)d_out;

    // ws layout: [0,4MB) f64 i_in partials | [4MB,+64KB) zmask | ZB partials
    char* ws = (char*)d_ws;
    double*       part  = (double*)ws;
    unsigned int* zmask = (unsigned int*)(ws + (4u << 20));
    float*        ZBp   = (float*)(ws + (4u << 20) + (64u << 10));

    size_t fixed = (4u << 20) + (64u << 10);
    size_t avail = ws_size > fixed ? ws_size - fixed : 0;
    int NC = 16;                                   // n-chunks for k3 (pow2)
    while (NC > 2 && (size_t)NC * 16 * KN * sizeof(float) > avail) NC >>= 1;
    int nper = NN / NC;                            // multiple of UN

    hipMemsetAsync(zmask, 0, NN * sizeof(unsigned int), stream);
    k1_gemm <<<dim3(32, 16), 64, 0, stream>>>(inputs, W, part);
    k2_point<<<128, 256, 0, stream>>>(part, old_v, old_spike, tt, out, zmask);
    k3_stream<<<dim3(56, NC), 256, 0, stream>>>((const float2*)Bw, zmask,
                                                (float2*)ZBp, nper);
    k4_gather<<<128, 256, 0, stream>>>(ZBp, ridx, out + 65536, NC);
}